// Round 15
// baseline (104.709 us; speedup 1.0000x reference)
//
#include <hip/hip_runtime.h>

// GSplat renderer — single fused persistent kernel.
// R5/R10/R12/R14 falsified latency/DS/occupancy/issue as accum bottlenecks;
// totals track ONLY memory traffic + launch plumbing. So: fuse everything.
// grid (32 tiles, 8 parts) = 256 blocks = 1/CU (all co-resident).
// Phase 1: per-block LDS tables (2 rounds x 128 g) + R14's packed-f32 loop,
//          partials [8][PIX] float4 pixel-major (8 MB).
// Barrier: device-scope atomic counter + threadfence (counter zeroed per
//          replay by a captured hipMemsetAsync).
// Phase 2: 1 px/thread, 8 independent float4 loads, div/clip/store.

constexpr int HH = 256;
constexpr int WW = 256;
constexpr int PIX = HH * WW;
constexpr int NCH = 128;      // gaussians per staging round
constexpr int ROUNDS = 2;     // 256 g per block = N/PARTS
constexpr int PARTS = 8;
constexpr int CPB = 64;
constexpr int RPB = 32;
constexpr int NBLK = 32 * PARTS;  // 256
constexpr float COORD_STEP = 2.0f / 255.0f;

typedef float f32x2 __attribute__((ext_vector_type(2)));

__device__ __forceinline__ unsigned bfr(float f) {  // f32 -> bf16 bits (RNE)
  unsigned u = __float_as_uint(f);
  return (u + 0x7fffu + ((u >> 16) & 1u)) >> 16;
}
__device__ __forceinline__ void pk_mul_blo(f32x2& d, f32x2 s, f32x2 v) {
  asm("v_pk_mul_f32 %0, %1, %2 op_sel:[0,0] op_sel_hi:[0,1]"
      : "=v"(d) : "v"(s), "v"(v));
}
__device__ __forceinline__ void pk_mul_bhi(f32x2& d, f32x2 s, f32x2 v) {
  asm("v_pk_mul_f32 %0, %1, %2 op_sel:[1,0] op_sel_hi:[1,1]"
      : "=v"(d) : "v"(s), "v"(v));
}
__device__ __forceinline__ void pk_fma_lo(f32x2& acc, f32x2 w, f32x2 c) {
  asm("v_pk_fma_f32 %0, %1, %2, %0 op_sel:[0,0,0] op_sel_hi:[0,1,1]"
      : "+v"(acc) : "v"(w), "v"(c));
}
__device__ __forceinline__ void pk_fma_hi(f32x2& acc, f32x2 w, f32x2 c) {
  asm("v_pk_fma_f32 %0, %1, %2, %0 op_sel:[1,0,0] op_sel_hi:[1,1,1]"
      : "+v"(acc) : "v"(w), "v"(c));
}

__global__ __launch_bounds__(256) void gs_fused(
    const float* __restrict__ means, const float* __restrict__ scales,
    const float* __restrict__ opac, const float* __restrict__ colors,
    float4* __restrict__ partials, unsigned* __restrict__ counter,
    float* __restrict__ out) {
  __shared__ float pxL[NCH], pyL[NCH], kL[NCH];
  __shared__ float4 colL[NCH];
  __shared__ float exL[NCH][CPB];   // 32 KB
  __shared__ uint4 packL[NCH][8];   // 16 KB

  const int t = threadIdx.x;
  const int tile = blockIdx.x;   // 0..31
  const int part = blockIdx.y;   // 0..7
  const int cb = tile & 3;       // col band 0..3
  const int rb = tile >> 2;      // row band 0..7

  const int c0 = (t & 31) << 1;  // local col pair
  const int rg = t >> 5;         // rowgroup 0..7 (4 rows)

  f32x2 z = {0.f, 0.f};
  f32x2 aRG_A0 = z, aBD_A0 = z, aRG_B0 = z, aBD_B0 = z;
  f32x2 aRG_A1 = z, aBD_A1 = z, aRG_B1 = z, aBD_B1 = z;
  f32x2 aRG_A2 = z, aBD_A2 = z, aRG_B2 = z, aBD_B2 = z;
  f32x2 aRG_A3 = z, aBD_A3 = z, aRG_B3 = z, aBD_B3 = z;

  for (int round = 0; round < ROUNDS; ++round) {
    const int n0 = part * (ROUNDS * NCH) + round * NCH;

    // --- stage params ---
    if (t < NCH) {
      int n = n0 + t;
      float mx = means[3 * n], my = means[3 * n + 1], mz = means[3 * n + 2];
      float scl = fmaxf((scales[3 * n] + scales[3 * n + 1] + scales[3 * n + 2]) * (1.0f / 3.0f), 1e-4f);
      float op = opac[n];
      float rzs = 1.0f / (fabsf(mz) + 1.0f);
      float sigma = fminf(fmaxf(scl * rzs, 0.02f), 0.5f);
      float inv_s = 1.0f / sigma;
      pxL[t] = tanhf(mx * rzs);
      pyL[t] = tanhf(my * rzs);
      kL[t] = -0.72134752044f * inv_s * inv_s;  // -0.5/ln2 * inv_s^2
      colL[t] = make_float4(op * colors[3 * n], op * colors[3 * n + 1],
                            op * colors[3 * n + 2], op);
    }
    __syncthreads();

    // --- stage tables ---
    {
      int c = t & 63;
      int jb = t >> 6;  // 0..3
      float ccol = -1.0f + COORD_STEP * (float)(cb * CPB + c);
#pragma unroll 8
      for (int jj = 0; jj < NCH / 4; ++jj) {
        int j = jb + (jj << 2);
        float dx = ccol - pxL[j];
        exL[j][c] = exp2f(kL[j] * dx * dx);
      }
#pragma unroll
      for (int k = 0; k < 4; ++k) {   // 1024 pack entries / 256 threads
        int e = t + (k << 8);
        int j = e >> 3;       // gaussian 0..127
        int rgf = e & 7;      // rowgroup 0..7
        int rbase = rb * RPB + (rgf << 2);
        float py = pyL[j], K = kL[j];
        float d0 = (-1.0f + COORD_STEP * (float)(rbase + 0)) - py;
        float d1 = (-1.0f + COORD_STEP * (float)(rbase + 1)) - py;
        float d2 = (-1.0f + COORD_STEP * (float)(rbase + 2)) - py;
        float d3 = (-1.0f + COORD_STEP * (float)(rbase + 3)) - py;
        float e0 = exp2f(K * d0 * d0);
        float e1 = exp2f(K * d1 * d1);
        float e2 = exp2f(K * d2 * d2);
        float e3 = exp2f(K * d3 * d3);
        float4 cv = colL[j];
        packL[j][rgf] = make_uint4(bfr(e0) | (bfr(e1) << 16),
                                   bfr(e2) | (bfr(e3) << 16),
                                   bfr(cv.x) | (bfr(cv.y) << 16),
                                   bfr(cv.z) | (bfr(cv.w) << 16));
      }
    }
    __syncthreads();

    // --- main contraction (R14 packed loop) ---
#pragma unroll 2
    for (int i = 0; i < NCH; ++i) {
      f32x2 exv = *(const f32x2*)&exL[i][c0];
      uint4 pk = packL[i][rg];
      f32x2 ey01 = {__uint_as_float(pk.x << 16),
                    __uint_as_float(pk.x & 0xffff0000u)};
      f32x2 ey23 = {__uint_as_float(pk.y << 16),
                    __uint_as_float(pk.y & 0xffff0000u)};
      f32x2 cRG = {__uint_as_float(pk.z << 16),
                   __uint_as_float(pk.z & 0xffff0000u)};
      f32x2 cBD = {__uint_as_float(pk.w << 16),
                   __uint_as_float(pk.w & 0xffff0000u)};
      f32x2 w0, w1, w2, w3;
      pk_mul_blo(w0, ey01, exv);
      pk_mul_bhi(w1, ey01, exv);
      pk_mul_blo(w2, ey23, exv);
      pk_mul_bhi(w3, ey23, exv);
      pk_fma_lo(aRG_A0, w0, cRG); pk_fma_lo(aBD_A0, w0, cBD);
      pk_fma_hi(aRG_B0, w0, cRG); pk_fma_hi(aBD_B0, w0, cBD);
      pk_fma_lo(aRG_A1, w1, cRG); pk_fma_lo(aBD_A1, w1, cBD);
      pk_fma_hi(aRG_B1, w1, cRG); pk_fma_hi(aBD_B1, w1, cBD);
      pk_fma_lo(aRG_A2, w2, cRG); pk_fma_lo(aBD_A2, w2, cBD);
      pk_fma_hi(aRG_B2, w2, cRG); pk_fma_hi(aBD_B2, w2, cBD);
      pk_fma_lo(aRG_A3, w3, cRG); pk_fma_lo(aBD_A3, w3, cBD);
      pk_fma_hi(aRG_B3, w3, cRG); pk_fma_hi(aBD_B3, w3, cBD);
    }
    __syncthreads();  // all reads done before next round overwrites LDS
  }

  // --- phase-1 epilogue: pixel-major float4 partials ---
  {
    float4* pb = partials + (size_t)part * PIX;
    int colabs = cb * CPB + c0;
    int rowb = rb * RPB + (rg << 2);
#define GS_ST(RG_A, BD_A, RG_B, BD_B, R)                          \
    { float4* rowp = pb + (rowb + (R)) * WW + colabs;             \
      rowp[0] = make_float4(RG_A.x, RG_A.y, BD_A.x, BD_A.y);      \
      rowp[1] = make_float4(RG_B.x, RG_B.y, BD_B.x, BD_B.y); }
    GS_ST(aRG_A0, aBD_A0, aRG_B0, aBD_B0, 0)
    GS_ST(aRG_A1, aBD_A1, aRG_B1, aBD_B1, 1)
    GS_ST(aRG_A2, aBD_A2, aRG_B2, aBD_B2, 2)
    GS_ST(aRG_A3, aBD_A3, aRG_B3, aBD_B3, 3)
#undef GS_ST
  }

  // --- device-wide barrier (all 256 blocks are co-resident: grid == #CUs) ---
  __threadfence();      // release this block's partials device-wide
  __syncthreads();
  if (t == 0) {
    atomicAdd(counter, 1u);
    while (atomicAdd(counter, 0u) < (unsigned)NBLK) {
      __builtin_amdgcn_s_sleep(8);
    }
  }
  __syncthreads();
  __threadfence();      // acquire

  // --- phase 2: finalize, 1 px/thread ---
  {
    int bid = blockIdx.x + (blockIdx.y << 5);   // 0..255
    int px = (bid << 8) + t;                    // 0..PIX-1
    float sr = 0.f, sg = 0.f, sb = 0.f, sd = 0.f;
#pragma unroll
    for (int p = 0; p < PARTS; ++p) {
      float4 v = partials[(size_t)p * PIX + px];
      sr += v.x; sg += v.y; sb += v.z; sd += v.w;
    }
    float inv = 1.0f / fmaxf(sd, 1e-5f);
    out[0 * PIX + px] = fminf(fmaxf(sr * inv, 0.0f), 1.0f);
    out[1 * PIX + px] = fminf(fmaxf(sg * inv, 0.0f), 1.0f);
    out[2 * PIX + px] = fminf(fmaxf(sb * inv, 0.0f), 1.0f);
  }
}

extern "C" void kernel_launch(void* const* d_in, const int* in_sizes, int n_in,
                              void* d_out, int out_size, void* d_ws, size_t ws_size,
                              hipStream_t stream) {
  const float* means = (const float*)d_in[0];
  // d_in[1] = quats (unused by reference)
  const float* scales = (const float*)d_in[2];
  const float* opac = (const float*)d_in[3];
  const float* colors = (const float*)d_in[4];
  float* out = (float*)d_out;

  // ws layout: partials [PARTS][PIX] float4 (8 MB), then barrier counter.
  float4* partials = (float4*)d_ws;
  unsigned* counter = (unsigned*)((char*)d_ws + (size_t)PARTS * PIX * sizeof(float4));

  // Zero the barrier counter every call (captured into the graph).
  hipMemsetAsync(counter, 0, 64, stream);
  gs_fused<<<dim3(32, PARTS), 256, 0, stream>>>(
      means, scales, opac, colors, partials, counter, out);
}

// Round 16
// 18.973 us; speedup vs baseline: 5.5189x; 5.5189x over previous
//
#include <hip/hip_runtime.h>

// GSplat renderer as a bf16 MFMA GEMM.
// out[(c,row), col] = sum_n A[(c,row),n] * B[n,col]
//   A[(c,row),n] = opcolor_c[n] * exp2(K_n dy^2)   (c=3 row: opacity/denom)
//   B[n,col]     = exp2(K_n dx^2)
// M=1024, N=256, K=2048 -> 1.07 GF -> ~1us of MFMA vs ~26us of VALU (R11-R14
// all issue-bound ~2.2x above any VALU model; pk_f32 null => scalar-rate ALU).
// Block: M-tile 64 (c = mt>>2 fixed), N-tile 64, K-chunk 256.
// Grid (16,4,8) = 512 blocks = 2/CU. LDS 68 KB: A[64][256] + Bt[64][256] bf16,
// XOR-swizzled (^(row&7)<<4) against the 512B-stride bank conflict.
// Fragment safety: A and B frags use the IDENTICAL [idx][k] lane formula, so
// any k-slot-order mis-guess is a permutation that cancels in the K-sum.
// C/D layout col=lane&15, row=(lane>>4)*4+reg is HW-verified (m89/m91).

constexpr int PIX = 65536;
constexpr int KCH = 256;     // K-chunk (gaussians per block)
constexpr int KSPLIT = 8;
constexpr int MT = 64;
constexpr int NT = 64;
constexpr float COORD_STEP = 2.0f / 255.0f;

typedef __attribute__((ext_vector_type(8))) short short8;
typedef __attribute__((ext_vector_type(4))) float f32x4;

__device__ __forceinline__ unsigned cvt_pk_bf16(float lo, float hi) {
  unsigned r;
  asm("v_cvt_pk_bf16_f32 %0, %1, %2" : "=v"(r) : "v"(lo), "v"(hi));
  return r;
}

__global__ __launch_bounds__(256) void gs_mfma(
    const float* __restrict__ means, const float* __restrict__ scales,
    const float* __restrict__ opac, const float* __restrict__ colors,
    float* __restrict__ partials) {
  __shared__ unsigned short A_l[MT * KCH];  // bf16 bits, swizzled rows
  __shared__ unsigned short B_l[NT * KCH];  // bf16 bits (n-major), swizzled
  __shared__ float pxL[KCH], pyL[KCH], kKL[KCH], colL[KCH];

  const int t = threadIdx.x;
  const int mt = blockIdx.x;          // 0..15: c = mt>>2, rowband (mt&3)*64
  const int nt = blockIdx.y;          // 0..3
  const int kp = blockIdx.z;          // 0..7
  const int c = mt >> 2;
  const int row0 = (mt & 3) * MT;
  const int col0 = nt * NT;

  // --- per-gaussian params for this K-chunk (1 per thread) ---
  {
    int n = kp * KCH + t;
    float mx = means[3 * n], my = means[3 * n + 1], mz = means[3 * n + 2];
    float scl = fmaxf((scales[3 * n] + scales[3 * n + 1] + scales[3 * n + 2]) * (1.0f / 3.0f), 1e-4f);
    float op = opac[n];
    float rzs = 1.0f / (fabsf(mz) + 1.0f);
    float sigma = fminf(fmaxf(scl * rzs, 0.02f), 0.5f);
    float inv_s = 1.0f / sigma;
    pxL[t] = tanhf(mx * rzs);
    pyL[t] = tanhf(my * rzs);
    kKL[t] = -0.72134752044f * inv_s * inv_s;  // -0.5/ln2 * inv_s^2
    colL[t] = (c < 3) ? op * colors[3 * n + c] : op;
  }
  __syncthreads();

  // --- stage A (ey*col) and Bt (ex) tiles, bf16, swizzled ---
  // Thread: 4 gaussians (kq..kq+3), 16 rows & 16 cols (mq..mq+15).
  {
    const int kq = (t & 63) << 2;       // element k base
    const int mq = (t >> 6) << 4;       // local row/col base
    const int kbyte = (t & 63) << 3;    // byte offset of the 4-bf16 group
    float py0 = pyL[kq + 0], py1 = pyL[kq + 1], py2 = pyL[kq + 2], py3 = pyL[kq + 3];
    float px0 = pxL[kq + 0], px1 = pxL[kq + 1], px2 = pxL[kq + 2], px3 = pxL[kq + 3];
    float K0 = kKL[kq + 0], K1 = kKL[kq + 1], K2 = kKL[kq + 2], K3 = kKL[kq + 3];
    float c0 = colL[kq + 0], c1 = colL[kq + 1], c2 = colL[kq + 2], c3 = colL[kq + 3];
#pragma unroll 4
    for (int j = 0; j < 16; ++j) {
      int m = mq + j;
      // A row m  (image row row0+m)
      float cr = -1.0f + COORD_STEP * (float)(row0 + m);
      float d0 = cr - py0, d1 = cr - py1, d2 = cr - py2, d3 = cr - py3;
      float e0 = exp2f(K0 * d0 * d0) * c0;
      float e1 = exp2f(K1 * d1 * d1) * c1;
      float e2 = exp2f(K2 * d2 * d2) * c2;
      float e3 = exp2f(K3 * d3 * d3) * c3;
      uint2 pa;
      pa.x = cvt_pk_bf16(e0, e1);
      pa.y = cvt_pk_bf16(e2, e3);
      *(uint2*)((char*)A_l + ((m * 512 + kbyte) ^ ((m & 7) << 4))) = pa;
      // Bt row m = image col col0+m
      float cc = -1.0f + COORD_STEP * (float)(col0 + m);
      float f0 = cc - px0, f1 = cc - px1, f2 = cc - px2, f3 = cc - px3;
      float g0 = exp2f(K0 * f0 * f0);
      float g1 = exp2f(K1 * f1 * f1);
      float g2 = exp2f(K2 * f2 * f2);
      float g3 = exp2f(K3 * f3 * f3);
      uint2 pb;
      pb.x = cvt_pk_bf16(g0, g1);
      pb.y = cvt_pk_bf16(g2, g3);
      *(uint2*)((char*)B_l + ((m * 512 + kbyte) ^ ((m & 7) << 4))) = pb;
    }
  }
  __syncthreads();

  // --- MFMA phase: wave w -> rows [w*16, +16), all 64 cols ---
  const int w = t >> 6;
  const int lr = t & 15;
  const int lg = (t >> 4) & 3;

  f32x4 acc0 = {0.f, 0.f, 0.f, 0.f};
  f32x4 acc1 = acc0, acc2 = acc0, acc3 = acc0;

  const int ra = w * 16 + lr;
  const unsigned offA = (unsigned)(ra * 512 + lg * 16);
  const unsigned swA = (unsigned)((ra & 7) << 4);
  const int nb0 = 0 * 16 + lr, nb1 = 1 * 16 + lr, nb2 = 2 * 16 + lr, nb3 = 3 * 16 + lr;
  const unsigned swB = (unsigned)((lr & 7) << 4);   // (nb&7) == (lr&7)
  const unsigned offB0 = (unsigned)(nb0 * 512 + lg * 16);
  const unsigned offB1 = (unsigned)(nb1 * 512 + lg * 16);
  const unsigned offB2 = (unsigned)(nb2 * 512 + lg * 16);
  const unsigned offB3 = (unsigned)(nb3 * 512 + lg * 16);

#pragma unroll
  for (int s = 0; s < 8; ++s) {
    const unsigned ks = (unsigned)(s * 64);
    short8 af = *(const short8*)((const char*)A_l + ((offA + ks) ^ swA));
    short8 b0 = *(const short8*)((const char*)B_l + ((offB0 + ks) ^ swB));
    short8 b1 = *(const short8*)((const char*)B_l + ((offB1 + ks) ^ swB));
    short8 b2 = *(const short8*)((const char*)B_l + ((offB2 + ks) ^ swB));
    short8 b3 = *(const short8*)((const char*)B_l + ((offB3 + ks) ^ swB));
    acc0 = __builtin_amdgcn_mfma_f32_16x16x32_bf16(af, b0, acc0, 0, 0, 0);
    acc1 = __builtin_amdgcn_mfma_f32_16x16x32_bf16(af, b1, acc1, 0, 0, 0);
    acc2 = __builtin_amdgcn_mfma_f32_16x16x32_bf16(af, b2, acc2, 0, 0, 0);
    acc3 = __builtin_amdgcn_mfma_f32_16x16x32_bf16(af, b3, acc3, 0, 0, 0);
  }

  // --- epilogue: D col=lane&15, row=lg*4+r (HW-verified m89/m91) ---
  {
    float* pb = partials +
        (((size_t)kp * 1024 + c * 256 + row0 + w * 16 + lg * 4) * 256) +
        col0 + lr;
#pragma unroll
    for (int r = 0; r < 4; ++r) {
      pb[r * 256 + 0]  = acc0[r];
      pb[r * 256 + 16] = acc1[r];
      pb[r * 256 + 32] = acc2[r];
      pb[r * 256 + 48] = acc3[r];
    }
  }
}

// grid = 256 blocks; thread = one pixel; 32 coalesced dword loads.
__global__ __launch_bounds__(256) void gs_finalize(
    const float* __restrict__ partials, float* __restrict__ out) {
  int px = blockIdx.x * 256 + threadIdx.x;
  int row = px >> 8, col = px & 255;
  float s0 = 0.f, s1 = 0.f, s2 = 0.f, s3 = 0.f;
#pragma unroll
  for (int kp = 0; kp < KSPLIT; ++kp) {
    const float* base = partials + (((size_t)kp * 4) * 256 + row) * 256 + col;
    s0 += base[0 * 65536];
    s1 += base[1 * 65536];
    s2 += base[2 * 65536];
    s3 += base[3 * 65536];
  }
  float inv = 1.0f / fmaxf(s3, 1e-5f);
  out[0 * PIX + px] = fminf(fmaxf(s0 * inv, 0.0f), 1.0f);
  out[1 * PIX + px] = fminf(fmaxf(s1 * inv, 0.0f), 1.0f);
  out[2 * PIX + px] = fminf(fmaxf(s2 * inv, 0.0f), 1.0f);
}

extern "C" void kernel_launch(void* const* d_in, const int* in_sizes, int n_in,
                              void* d_out, int out_size, void* d_ws, size_t ws_size,
                              hipStream_t stream) {
  const float* means = (const float*)d_in[0];
  // d_in[1] = quats (unused by reference)
  const float* scales = (const float*)d_in[2];
  const float* opac = (const float*)d_in[3];
  const float* colors = (const float*)d_in[4];
  float* out = (float*)d_out;

  // ws: partials [KSPLIT][1024][256] fp32 = 8 MB
  float* partials = (float*)d_ws;

  gs_mfma<<<dim3(16, 4, KSPLIT), 256, 0, stream>>>(
      means, scales, opac, colors, partials);
  gs_finalize<<<256, 256, 0, stream>>>(partials, out);
}